// Round 3
// baseline (589.276 us; speedup 1.0000x reference)
//
#include <hip/hip_runtime.h>

// Luong dot attention, B=8, T=S=2048, D=1024, fp32 in/out.
// Fast path (ws >= 192 MiB):
//   P1: trg -> fp16 (plain row-major)
//   P2: src -> Bh'/Bl' (G1 fragment-order) + T' (G2 fragment-order)
//   G1: scores = trg16 @ src^T; A LDS-staged (triple-buf, bank-perfect),
//       B hi/lo loaded fragment-direct global->VGPR, prefetched 1 phase ahead;
//       2 lockstep phases/K-tile, counted vmcnt (peeled exact tails).
//   SM: softmax fp32 in place + fp16 weights (single-wave blocks)
//   G2: context = w16 @ srcT; same structure, B = T' fragment-direct.
// Fallback = round-1 kernels.

#define BB 8
#define TT 2048
#define SS 2048
#define DD 1024

typedef float  f32x4   __attribute__((ext_vector_type(4)));
typedef float  f32x16  __attribute__((ext_vector_type(16)));
typedef short  bf16x8  __attribute__((ext_vector_type(8)));
typedef _Float16 f16x8 __attribute__((ext_vector_type(8)));
typedef _Float16 f16x4 __attribute__((ext_vector_type(4)));

static __device__ __forceinline__ unsigned short bf16_rne(float x) {
  unsigned int u = __float_as_uint(x);
  u += 0x7FFFu + ((u >> 16) & 1u);
  return (unsigned short)(u >> 16);
}

static __device__ __forceinline__ void gl2lds16(const void* g, void* l) {
  __builtin_amdgcn_global_load_lds(
      (const __attribute__((address_space(1))) unsigned int*)g,
      (__attribute__((address_space(3))) unsigned int*)l, 16, 0, 0);
}

// Bank-perfect LDS layout for a 256x16-half region.
// Row r, half h: halves offset = (r>>2)*64 + (2*(r&3) + (h ^ ((r>>2)&1)))*8.
static __device__ __forceinline__ int ldsoff_h(int r, int h) {
  return ((r >> 2) << 6) + ((((r & 3) << 1) + (h ^ ((r >> 2) & 1))) << 3);
}

// ---------------------------------------------------------------------------
// P1: trg fp32 -> fp16 (plain).
// ---------------------------------------------------------------------------
__global__ __launch_bounds__(256)
void conv_trg_f16(const float* __restrict__ x, _Float16* __restrict__ h16) {
  const size_t i = ((size_t)blockIdx.x * 256 + threadIdx.x) * 8;
  float4 v0 = *(const float4*)(x + i);
  float4 v1 = *(const float4*)(x + i + 4);
  f16x8 h;
  h[0] = (_Float16)v0.x; h[1] = (_Float16)v0.y;
  h[2] = (_Float16)v0.z; h[3] = (_Float16)v0.w;
  h[4] = (_Float16)v1.x; h[5] = (_Float16)v1.y;
  h[6] = (_Float16)v1.z; h[7] = (_Float16)v1.w;
  *(f16x8*)(h16 + i) = h;
}

// ---------------------------------------------------------------------------
// P2: src -> fragment-order Bh'/Bl' and T'.
// Bh'/Bl' (for G1): addr(b,s,d) = (b*64 + (d>>4))*32768 + (s>>5)*512
//                                 + (((d>>3)&1)*32 + (s&31))*8 + (d&7)
// T' (for G2):      addr(b,d,s) = (b*128 + (s>>4))*16384 + (d>>5)*512
//                                 + (((s>>3)&1)*32 + (d&31))*8 + (s&7)
// ---------------------------------------------------------------------------
__global__ __launch_bounds__(256)
void conv_src_frag(const float* __restrict__ src,
                   _Float16* __restrict__ bhp,
                   _Float16* __restrict__ blp,
                   _Float16* __restrict__ tp) {
  const int b  = blockIdx.z;
  const int d0 = blockIdx.x * 64;
  const int s0 = blockIdx.y * 64;
  const float* S = src + (size_t)b * SS * DD;
  __shared__ _Float16 t16[64][65];
  const int t = threadIdx.x;

  // Phase A: 512 chunks (srow, dgrp); dgrp fastest for coalesced reads.
#pragma unroll
  for (int p = 0; p < 2; ++p) {
    const int idx  = p * 256 + t;
    const int dgrp = idx & 7;
    const int srow = idx >> 3;            // [0,64)
    const float* g = S + (size_t)(s0 + srow) * DD + d0 + dgrp * 8;
    float4 v0 = *(const float4*)g;
    float4 v1 = *(const float4*)(g + 4);
    float f[8] = {v0.x, v0.y, v0.z, v0.w, v1.x, v1.y, v1.z, v1.w};
    f16x8 h, l;
#pragma unroll
    for (int e = 0; e < 8; ++e) {
      _Float16 hv = (_Float16)f[e];
      h[e] = hv;
      l[e] = (_Float16)(f[e] - (float)hv);
      t16[srow][dgrp * 8 + e] = hv;
    }
    const int d   = d0 + dgrp * 8;
    const int s   = s0 + srow;
    const size_t base = ((size_t)b * 64 + (d >> 4)) * 32768 +
                        (size_t)(s >> 5) * 512 +
                        (size_t)((((d >> 3) & 1) * 32 + (s & 31)) * 8);
    *(f16x8*)(bhp + base) = h;
    *(f16x8*)(blp + base) = l;
  }
  __syncthreads();
  // Phase B: 512 chunks (d64, sgrp); d64 fastest for coalesced writes.
#pragma unroll
  for (int p = 0; p < 2; ++p) {
    const int d64  = t & 63;
    const int sgrp = p * 4 + (t >> 6);    // [0,8)
    f16x8 o;
#pragma unroll
    for (int k = 0; k < 8; ++k) o[k] = t16[sgrp * 8 + k][d64];
    const int d = d0 + d64;
    const int s = s0 + sgrp * 8;
    const size_t base = ((size_t)b * 128 + (s >> 4)) * 16384 +
                        (size_t)(d >> 5) * 512 +
                        (size_t)((((s >> 3) & 1) * 32 + (d & 31)) * 8);
    *(f16x8*)(tp + base) = o;
  }
}

// ---------------------------------------------------------------------------
// G1: scores = trg16 @ src16^T, fp16 2-pass (B hi+lo direct-from-global).
// 256x256 tile, BK=32, 8 waves (2Mx4N, per-wave 128x64), 32x32x16 MFMA.
// LDS: A only, 3 x 16 KB, bank-perfect. Phase index P = 2*tt+kk in [0,64).
// Per phase: ds_read A x4 | load B(P+1) x4 | gl2lds A(tt+2) x1 |
//            vmcnt(6) | barrier | lgkm(0) | 16 MFMA | barrier.
// ---------------------------------------------------------------------------
__global__ __launch_bounds__(512, 2)
void attn_gemm1_pipe(const _Float16* __restrict__ a16,
                     const _Float16* __restrict__ bhp,
                     const _Float16* __restrict__ blp,
                     float* __restrict__ scores) {
  const int b   = blockIdx.z;
  const int tm0 = blockIdx.y * 256;
  const int tn0 = blockIdx.x * 256;
  float* C = scores + (size_t)b * TT * SS;

  __shared__ __align__(16) _Float16 sm[3][8192];   // 48 KB

  const int t      = threadIdx.x;            // 0..511
  const int lane   = t & 63;
  const int wv     = t >> 6;                 // 0..7
  const int wm     = (wv >> 2) * 128;
  const int wn     = (wv & 3) * 64;
  const int lrow32 = lane & 31;
  const int khalf  = lane >> 5;

  // A staging: one 16B chunk per thread per region (inverse of ldsoff_h).
  const int ar = (t >> 3) * 4 + ((t & 7) >> 1);
  const int ah = ((t & 7) & 1) ^ ((t >> 3) & 1);
  const _Float16* gpA0 = a16 + ((size_t)b * TT + tm0 + ar) * DD + ah * 8;
  const _Float16* gpA1 = gpA0 + 16;

  // B fragment bases (per-lane folded in).
  const _Float16* bh_base = bhp + (size_t)b * 2097152 +
                            (size_t)((tn0 + wn) >> 5) * 512 + (size_t)lane * 8;
  const _Float16* bl_base = blp + (size_t)b * 2097152 +
                            (size_t)((tn0 + wn) >> 5) * 512 + (size_t)lane * 8;

  int aoff[4];
#pragma unroll
  for (int mi = 0; mi < 4; ++mi)
    aoff[mi] = ldsoff_h(wm + mi * 32 + lrow32, khalf);

  f32x16 acc[4][2];
#pragma unroll
  for (int i = 0; i < 4; ++i)
#pragma unroll
    for (int j = 0; j < 2; ++j) acc[i][j] = (f32x16)0.0f;

  f16x8 bhA[2], blA[2], bhB[2], blB[2];

  _Float16* bufc = sm[0];
  _Float16* bufo = sm[1];
  _Float16* bufn = sm[2];

#define G1_LOADB(QQ, BH, BL)                                                \
  do {                                                                      \
    BH[0] = *(const f16x8*)(bh_base + (size_t)(QQ) * 32768);                \
    BH[1] = *(const f16x8*)(bh_base + (size_t)(QQ) * 32768 + 512);          \
    BL[0] = *(const f16x8*)(bl_base + (size_t)(QQ) * 32768);                \
    BL[1] = *(const f16x8*)(bl_base + (size_t)(QQ) * 32768 + 512);          \
  } while (0)

#define G1_PHASE(AOFFADD, DOLOADB, QN, BHN, BLN, DOSTAGE, AJ, VM, BHC, BLC) \
  {                                                                         \
    f16x8 af[4];                                                            \
    _Pragma("unroll") for (int mi = 0; mi < 4; ++mi)                        \
      af[mi] = *(const f16x8*)(bufc + (AOFFADD) + aoff[mi]);                \
    asm volatile("" ::: "memory");                                          \
    if (DOLOADB) { G1_LOADB(QN, BHN, BLN); }                                \
    asm volatile("" ::: "memory");                                          \
    if (DOSTAGE) {                                                          \
      gl2lds16((AJ) ? (const void*)gpA1 : (const void*)gpA0,                \
               bufn + (AJ) * 4096 + t * 8);                                 \
    }                                                                       \
    asm volatile("s_waitcnt vmcnt(" #VM ")" ::: "memory");                  \
    __builtin_amdgcn_s_barrier();                                           \
    asm volatile("s_waitcnt lgkmcnt(0)" ::: "memory");                      \
    __builtin_amdgcn_sched_barrier(0);                                      \
    __builtin_amdgcn_s_setprio(1);                                          \
    _Pragma("unroll") for (int mi = 0; mi < 4; ++mi)                        \
      _Pragma("unroll") for (int ni = 0; ni < 2; ++ni) {                    \
        acc[mi][ni] = __builtin_amdgcn_mfma_f32_32x32x16_f16(af[mi], BHC[ni], acc[mi][ni], 0, 0, 0); \
        acc[mi][ni] = __builtin_amdgcn_mfma_f32_32x32x16_f16(af[mi], BLC[ni], acc[mi][ni], 0, 0, 0); \
      }                                                                     \
    __builtin_amdgcn_s_setprio(0);                                          \
    __builtin_amdgcn_s_barrier();                                           \
    __builtin_amdgcn_sched_barrier(0);                                      \
  }

  // Prologue: A(t0), B(P0), A(t1); wait leaves only A(t1) outstanding.
  gl2lds16(gpA0, sm[0] + t * 8);
  gl2lds16(gpA1, sm[0] + 4096 + t * 8);
  gpA0 += 32; gpA1 += 32;
  asm volatile("" ::: "memory");
  G1_LOADB(0, bhA, blA);
  asm volatile("" ::: "memory");
  gl2lds16(gpA0, sm[1] + t * 8);
  gl2lds16(gpA1, sm[1] + 4096 + t * 8);
  gpA0 += 32; gpA1 += 32;
  asm volatile("s_waitcnt vmcnt(2)" ::: "memory");
  __builtin_amdgcn_s_barrier();
  __builtin_amdgcn_sched_barrier(0);

#pragma unroll 1
  for (int tt = 0; tt < 30; ++tt) {
    G1_PHASE(0,    1, 2 * tt + 1, bhB, blB, 1, 0, 6, bhA, blA);
    G1_PHASE(4096, 1, 2 * tt + 2, bhA, blA, 1, 1, 6, bhB, blB);
    gpA0 += 32; gpA1 += 32;
    _Float16* tmp = bufc; bufc = bufo; bufo = bufn; bufn = tmp;
  }
  // tile 30
  G1_PHASE(0,    1, 61, bhB, blB, 0, 0, 5, bhA, blA);
  G1_PHASE(4096, 1, 62, bhA, blA, 0, 1, 4, bhB, blB);
  { _Float16* tmp = bufc; bufc = bufo; bufo = bufn; bufn = tmp; }
  // tile 31
  G1_PHASE(0,    1, 63, bhB, blB, 0, 0, 4, bhA, blA);
  G1_PHASE(4096, 0, 0,  bhA, blA, 0, 1, 0, bhB, blB);

#undef G1_PHASE
#undef G1_LOADB

  // C/D 32x32: col=lane&31, row=(p&3)+8*(p>>2)+4*(lane>>5)
  const int rsub = 4 * khalf;
#pragma unroll
  for (int mi = 0; mi < 4; ++mi)
#pragma unroll
    for (int ni = 0; ni < 2; ++ni) {
      const int rb  = tm0 + wm + mi * 32 + rsub;
      const int col = tn0 + wn + ni * 32 + lrow32;
#pragma unroll
      for (int p = 0; p < 16; ++p)
        C[(size_t)(rb + (p & 3) + 8 * (p >> 2)) * SS + col] = acc[mi][ni][p];
    }
}

// ---------------------------------------------------------------------------
// SM: single-wave blocks. 32 floats/lane, shuffle-only.
// ---------------------------------------------------------------------------
__global__ __launch_bounds__(64)
void attn_softmax_w16(float* __restrict__ w, _Float16* __restrict__ w16) {
  const size_t row = blockIdx.x;
  float4* p4 = (float4*)(w + row * SS);
  _Float16* o = w16 + row * SS;
  const int lane = threadIdx.x;

  float4 v[8];
#pragma unroll
  for (int j = 0; j < 8; ++j) v[j] = p4[lane + 64 * j];

  float m = -1e30f;
#pragma unroll
  for (int j = 0; j < 8; ++j)
    m = fmaxf(m, fmaxf(fmaxf(v[j].x, v[j].y), fmaxf(v[j].z, v[j].w)));
#pragma unroll
  for (int off = 32; off >= 1; off >>= 1) m = fmaxf(m, __shfl_xor(m, off, 64));

  float s = 0.0f;
#pragma unroll
  for (int j = 0; j < 8; ++j) {
    v[j].x = __expf(v[j].x - m); v[j].y = __expf(v[j].y - m);
    v[j].z = __expf(v[j].z - m); v[j].w = __expf(v[j].w - m);
    s += v[j].x + v[j].y + v[j].z + v[j].w;
  }
#pragma unroll
  for (int off = 32; off >= 1; off >>= 1) s += __shfl_xor(s, off, 64);

  const float inv = __fdividef(1.0f, s);
#pragma unroll
  for (int j = 0; j < 8; ++j) {
    v[j].x *= inv; v[j].y *= inv; v[j].z *= inv; v[j].w *= inv;
    p4[lane + 64 * j] = v[j];
    f16x4 h;
    h[0] = (_Float16)v[j].x; h[1] = (_Float16)v[j].y;
    h[2] = (_Float16)v[j].z; h[3] = (_Float16)v[j].w;
    *(f16x4*)(o + 4 * (lane + 64 * j)) = h;
  }
}

// ---------------------------------------------------------------------------
// G2: context = w16 @ srcT (T' fragment-direct). Same structure as G1.
// Phase index Q = 2*tt+kk in [0,128). Steady vmcnt(4).
// ---------------------------------------------------------------------------
__global__ __launch_bounds__(512, 2)
void attn_gemm2_pipe(const _Float16* __restrict__ w16,
                     const _Float16* __restrict__ tp,
                     float* __restrict__ out) {
  const int b   = blockIdx.z;
  const int tm0 = blockIdx.y * 256;
  const int tn0 = blockIdx.x * 256;
  float* C = out + (size_t)b * TT * DD;

  __shared__ __align__(16) _Float16 sm[3][8192];   // 48 KB

  const int t      = threadIdx.x;
  const int lane   = t & 63;
  const int wv     = t >> 6;
  const int wm     = (wv >> 2) * 128;
  const int wn     = (wv & 3) * 64;
  const int lrow32 = lane & 31;
  const int khalf  = lane >> 5;

  const int ar = (t >> 3) * 4 + ((t & 7) >> 1);
  const int ah = ((t & 7) & 1) ^ ((t >> 3) & 1);
  const _Float16* gpA0 = w16 + ((size_t)b * TT + tm0 + ar) * SS + ah * 8;
  const _Float16* gpA1 = gpA0 + 16;

  const _Float16* tb_base = tp + (size_t)b * 2097152 +
                            (size_t)((tn0 + wn) >> 5) * 512 + (size_t)lane * 8;

  int aoff[4];
#pragma unroll
  for (int mi = 0; mi < 4; ++mi)
    aoff[mi] = ldsoff_h(wm + mi * 32 + lrow32, khalf);

  f32x16 acc[4][2];
#pragma unroll
  for (int i = 0; i < 4; ++i)
#pragma unroll
    for (int j = 0; j < 2; ++j) acc[i][j] = (f32x16)0.0f;

  f16x8 bfA[2], bfB[2];

  _Float16* bufc = sm[0];
  _Float16* bufo = sm[1];
  _Float16* bufn = sm[2];

#define G2_LOADB(QQ, BF)                                                    \
  do {                                                                      \
    BF[0] = *(const f16x8*)(tb_base + (size_t)(QQ) * 16384);                \
    BF[1] = *(const f16x8*)(tb_base + (size_t)(QQ) * 16384 + 512);          \
  } while (0)

#define G2_PHASE(AOFFADD, DOLOADB, QN, BFN, DOSTAGE, AJ, VM, BFC)           \
  {                                                                         \
    f16x8 af[4];                                                            \
    _Pragma("unroll") for (int mi = 0; mi < 4; ++mi)                        \
      af[mi] = *(const f16x8*)(bufc + (AOFFADD) + aoff[mi]);                \
    asm volatile("" ::: "memory");                                          \
    if (DOLOADB) { G2_LOADB(QN, BFN); }                                     \
    asm volatile("" ::: "memory");                                          \
    if (DOSTAGE) {                                                          \
      gl2lds16((AJ) ? (const void*)gpA1 : (const void*)gpA0,                \
               bufn + (AJ) * 4096 + t * 8);                                 \
    }                                                                       \
    asm volatile("s_waitcnt vmcnt(" #VM ")" ::: "memory");                  \
    __builtin_amdgcn_s_barrier();                                           \
    asm volatile("s_waitcnt lgkmcnt(0)" ::: "memory");                      \
    __builtin_amdgcn_sched_barrier(0);                                      \
    __builtin_amdgcn_s_setprio(1);                                          \
    _Pragma("unroll") for (int mi = 0; mi < 4; ++mi)                        \
      _Pragma("unroll") for (int ni = 0; ni < 2; ++ni)                      \
        acc[mi][ni] = __builtin_amdgcn_mfma_f32_32x32x16_f16(af[mi], BFC[ni], acc[mi][ni], 0, 0, 0); \
    __builtin_amdgcn_s_setprio(0);                                          \
    __builtin_amdgcn_s_barrier();                                           \
    __builtin_amdgcn_sched_barrier(0);                                      \
  }

  gl2lds16(gpA0, sm[0] + t * 8);
  gl2lds16(gpA1, sm[0] + 4096 + t * 8);
  gpA0 += 32; gpA1 += 32;
  asm volatile("" ::: "memory");
  G2_LOADB(0, bfA);
  asm volatile("" ::: "memory");
  gl2lds16(gpA0, sm[1] + t * 8);
  gl2lds16(gpA1, sm[1] + 4096 + t * 8);
  gpA0 += 32; gpA1 += 32;
  asm volatile("s_waitcnt vmcnt(2)" ::: "memory");
  __builtin_amdgcn_s_barrier();
  __builtin_amdgcn_sched_barrier(0);

#pragma unroll 1
  for (int tt = 0; tt < 62; ++tt) {
    G2_PHASE(0,    1, 2 * tt + 1, bfB, 1, 0, 4, bfA);
    G2_PHASE(4096, 1, 2 * tt + 2, bfA, 1, 1, 4, bfB);
    gpA0 += 32; gpA1 += 32;
    _Float16* tmp = bufc; bufc = bufo; bufo = bufn; bufn = tmp;
  }
  // tile 62
  G2_PHASE(0,    1, 125, bfB, 0, 0, 3, bfA);
  G2_PHASE(4096, 1, 126, bfA, 0, 1, 2, bfB);
  { _Float16* tmp = bufc; bufc = bufo; bufo = bufn; bufn = tmp; }
  // tile 63
  G2_PHASE(0,    1, 127, bfB, 0, 0, 2, bfA);
  G2_PHASE(4096, 0, 0,   bfA, 0, 1, 0, bfB);

#undef G2_PHASE
#undef G2_LOADB

  const int rsub = 4 * khalf;
#pragma unroll
  for (int mi = 0; mi < 4; ++mi)
#pragma unroll
    for (int ni = 0; ni < 2; ++ni) {
      const int rb  = tm0 + wm + mi * 32 + rsub;
      const int col = tn0 + wn + ni * 32 + lrow32;
#pragma unroll
      for (int p = 0; p < 16; ++p)
        C[(size_t)(rb + (p & 3) + 8 * (p >> 2)) * DD + col] = acc[mi][ni][p];
    }
}

// ===========================================================================
// Fallback path (round-1 kernels, no workspace).
// ===========================================================================
__global__ __launch_bounds__(256, 1)
void attn_gemm1_scores_bf16x3(const float* __restrict__ trg,
                              const float* __restrict__ src,
                              float* __restrict__ scores) {
  const int b   = blockIdx.z;
  const int tm0 = blockIdx.y * 128;
  const int tn0 = blockIdx.x * 128;
  const float* A  = trg + (size_t)b * TT * DD;
  const float* Bm = src + (size_t)b * SS * DD;
  float* C = scores + (size_t)b * TT * SS;

  __shared__ __align__(16) unsigned short smAh[128 * 32];
  __shared__ __align__(16) unsigned short smAl[128 * 32];
  __shared__ __align__(16) unsigned short smBh[128 * 32];
  __shared__ __align__(16) unsigned short smBl[128 * 32];

  const int t     = threadIdx.x;
  const int lane  = t & 63;
  const int wv    = t >> 6;
  const int m_off = (wv & 1) * 64;
  const int n_off = (wv >> 1) * 64;
  const int q     = lane >> 4;
  const int lrow  = lane & 15;

  f32x4 acc[4][4];
#pragma unroll
  for (int i = 0; i < 4; ++i)
#pragma unroll
    for (int j = 0; j < 4; ++j) acc[i][j] = (f32x4)0.0f;

  for (int kt = 0; kt < DD; kt += 32) {
    __syncthreads();
#pragma unroll
    for (int h = 0; h < 2; ++h) {
      const int c  = t + h * 256;
      const int r  = c >> 2;
      const int j  = c & 3;
      const int gk = j ^ ((r >> 1) & 3);
      {
        const float* ga = A + (size_t)(tm0 + r) * DD + kt + gk * 8;
        float4 v0 = *(const float4*)ga;
        float4 v1 = *(const float4*)(ga + 4);
        float f[8] = {v0.x, v0.y, v0.z, v0.w, v1.x, v1.y, v1.z, v1.w};
        bf16x8 hi, lo;
#pragma unroll
        for (int e = 0; e < 8; ++e) {
          unsigned short hb = bf16_rne(f[e]);
          hi[e] = (short)hb;
          float hf = __uint_as_float(((unsigned int)hb) << 16);
          lo[e] = (short)bf16_rne(f[e] - hf);
        }
        *(bf16x8*)(smAh + c * 8) = hi;
        *(bf16x8*)(smAl + c * 8) = lo;
      }
      {
        const float* gb = Bm + (size_t)(tn0 + r) * DD + kt + gk * 8;
        float4 v0 = *(const float4*)gb;
        float4 v1 = *(const float4*)(gb + 4);
        float f[8] = {v0.x, v0.y, v0.z, v0.w, v1.x, v1.y, v1.z, v1.w};
        bf16x8 hi, lo;
#pragma unroll
        for (int e = 0; e < 8; ++e) {
          unsigned short hb = bf16_rne(f[e]);
          hi[e] = (short)hb;
          float hf = __uint_as_float(((unsigned int)hb) << 16);
          lo[e] = (short)bf16_rne(f[e] - hf);
        }
        *(bf16x8*)(smBh + c * 8) = hi;
        *(bf16x8*)(smBl + c * 8) = lo;
      }
    }
    __syncthreads();

    bf16x8 ah[4], al[4], bh[4], bl[4];
#pragma unroll
    for (int mi = 0; mi < 4; ++mi) {
      const int r   = m_off + mi * 16 + lrow;
      const int off = (r * 4 + (q ^ ((r >> 1) & 3))) * 8;
      ah[mi] = *(const bf16x8*)(smAh + off);
      al[mi] = *(const bf16x8*)(smAl + off);
    }
#pragma unroll
    for (int ni = 0; ni < 4; ++ni) {
      const int r   = n_off + ni * 16 + lrow;
      const int off = (r * 4 + (q ^ ((r >> 1) & 3))) * 8;
      bh[ni] = *(const bf16x8*)(smBh + off);
      bl[ni] = *(const bf16x8*)(smBl + off);
    }
#pragma unroll
    for (int mi = 0; mi < 4; ++mi)
#pragma unroll
      for (int ni = 0; ni < 4; ++ni) {
        acc[mi][ni] = __builtin_amdgcn_mfma_f32_16x16x32_bf16(al[mi], bh[ni], acc[mi][ni], 0, 0, 0);
        acc[mi][ni] = __builtin_amdgcn_mfma_f32_16x16x32_bf16(ah[mi], bl[ni], acc[mi][ni], 0, 0, 0);
        acc[mi][ni] = __builtin_amdgcn_mfma_f32_16x16x32_bf16(ah[mi], bh[ni], acc[mi][ni], 0, 0, 0);
      }
  }

#pragma unroll
  for (int mi = 0; mi < 4; ++mi)
#pragma unroll
    for (int ni = 0; ni < 4; ++ni) {
      const int row0 = tm0 + m_off + mi * 16 + q * 4;
      const int col  = tn0 + n_off + ni * 16 + lrow;
#pragma unroll
      for (int p = 0; p < 4; ++p)
        C[(size_t)(row0 + p) * SS + col] = acc[mi][ni][p];
    }
}

__global__ __launch_bounds__(256)
void attn_softmax_rows(float* __restrict__ w) {
  float* p = w + (size_t)blockIdx.x * SS;
  const int t = threadIdx.x;
  float4* p4 = (float4*)p;
  float4 v0 = p4[t];
  float4 v1 = p4[t + 256];

  float m = fmaxf(fmaxf(fmaxf(v0.x, v0.y), fmaxf(v0.z, v0.w)),
                  fmaxf(fmaxf(v1.x, v1.y), fmaxf(v1.z, v1.w)));
#pragma unroll
  for (int off = 32; off >= 1; off >>= 1) m = fmaxf(m, __shfl_xor(m, off, 64));
  __shared__ float redm[4];
  __shared__ float reds[4];
  const int wv = t >> 6, lane = t & 63;
  if (lane == 0) redm[wv] = m;
  __syncthreads();
  m = fmaxf(fmaxf(redm[0], redm[1]), fmaxf(redm[2], redm[3]));

  v0.x = __expf(v0.x - m); v0.y = __expf(v0.y - m);
  v0.z = __expf(v0.z - m); v0.w = __expf(v0.w - m);
  v1.x = __expf(v1.x - m); v1.y = __expf(v1.y - m);
  v1.z = __expf(v1.z - m); v1.w = __expf(v1.w - m);

  float s = v0.x + v0.y + v0.z + v0.w + v1.x + v1.y + v1.z + v1.w;
#pragma unroll
  for (int off = 32; off >= 1; off >>= 1) s += __shfl_xor(s, off, 64);
  if (lane == 0) reds[wv] = s;
  __syncthreads();
  s = reds[0] + reds[1] + reds[2] + reds[3];

  const float inv = __fdividef(1.0f, s);
  v0.x *= inv; v0.y *= inv; v0.z *= inv; v0.w *= inv;
  v1.x *= inv; v1.y *= inv; v1.z *= inv; v1.w *= inv;
  p4[t] = v0;
  p4[t + 256] = v1;
}

__global__ __launch_bounds__(256, 1)
void attn_gemm2_ctx_f16(const float* __restrict__ w,
                        const float* __restrict__ src,
                        float* __restrict__ out) {
  const int b   = blockIdx.z;
  const int tm0 = blockIdx.y * 128;
  const int tn0 = blockIdx.x * 128;
  const float* A  = w + (size_t)b * TT * SS;
  const float* Bs = src + (size_t)b * SS * DD;
  float* C = out + (size_t)b * TT * DD;

  __shared__ __align__(16) _Float16 smA[128 * 32];
  __shared__ __align__(16) _Float16 smB[128 * 32];

  const int t     = threadIdx.x;
  const int lane  = t & 63;
  const int wv    = t >> 6;
  const int m_off = (wv & 1) * 64;
  const int n_off = (wv >> 1) * 64;
  const int q     = lane >> 4;
  const int lrow  = lane & 15;

  const int bn    = t & 127;
  const int bh2   = t >> 7;
  const int bs2   = (bn >> 1) & 3;
  const int slot0 = (2 * bh2) ^ bs2;
  const int slot1 = (2 * bh2 + 1) ^ bs2;

  f32x4 acc[4][4];
#pragma unroll
  for (int i = 0; i < 4; ++i)
#pragma unroll
    for (int j = 0; j < 4; ++j) acc[i][j] = (f32x4)0.0f;

  for (int kt = 0; kt < SS; kt += 32) {
    __syncthreads();
#pragma unroll
    for (int h = 0; h < 2; ++h) {
      const int c  = t + h * 256;
      const int r  = c >> 2;
      const int j  = c & 3;
      const int gk = j ^ ((r >> 1) & 3);
      const float* ga = A + (size_t)(tm0 + r) * SS + kt + gk * 8;
      float4 v0 = *(const float4*)ga;
      float4 v1 = *(const float4*)(ga + 4);
      f16x8 hv;
      hv[0] = (_Float16)v0.x; hv[1] = (_Float16)v0.y;
      hv[2] = (_Float16)v0.z; hv[3] = (_Float16)v0.w;
      hv[4] = (_Float16)v1.x; hv[5] = (_Float16)v1.y;
      hv[6] = (_Float16)v1.z; hv[7] = (_Float16)v1.w;
      *(f16x8*)(smA + c * 8) = hv;
    }
    {
      const float* gb = Bs + (size_t)(kt + bh2 * 16) * DD + (tn0 + bn);
      f16x8 c0, c1;
#pragma unroll
      for (int kk = 0; kk < 8; ++kk) c0[kk] = (_Float16)gb[(size_t)kk * DD];
#pragma unroll
      for (int kk = 0; kk < 8; ++kk) c1[kk] = (_Float16)gb[(size_t)(kk + 8) * DD];
      *(f16x8*)(smB + bn * 32 + slot0 * 8) = c0;
      *(f16x8*)(smB + bn * 32 + slot1 * 8) = c1;
    }
    __syncthreads();

    f16x8 af[4], bfr[4];
#pragma unroll
    for (int mi = 0; mi < 4; ++mi) {
      const int r   = m_off + mi * 16 + lrow;
      const int off = (r * 4 + (q ^ ((r >> 1) & 3))) * 8;
      af[mi] = *(const f16x8*)(smA + off);
    }
#pragma unroll
    for (int ni = 0; ni < 4; ++ni) {
      const int n   = n_off + ni * 16 + lrow;
      const int off = n * 32 + (q ^ ((n >> 1) & 3)) * 8;
      bfr[ni] = *(const f16x8*)(smB + off);
    }
#pragma unroll
    for (int mi = 0; mi < 4; ++mi)
#pragma unroll
      for (int ni = 0; ni < 4; ++ni)
        acc[mi][ni] = __builtin_amdgcn_mfma_f32_16x16x32_f16(af[mi], bfr[ni], acc[mi][ni], 0, 0, 0);
  }

#pragma unroll
  for (int mi = 0; mi < 4; ++mi)
#pragma unroll
    for (int ni = 0; ni < 4; ++ni) {
      const int row0 = tm0 + m_off + mi * 16 + q * 4;
      const int col  = tn0 + n_off + ni * 16 + lrow;
#pragma unroll
      for (int p = 0; p < 4; ++p)
        C[(size_t)(row0 + p) * DD + col] = acc[mi][ni][p];
    }
}

extern "C" void kernel_launch(void* const* d_in, const int* in_sizes, int n_in,
                              void* d_out, int out_size, void* d_ws, size_t ws_size,
                              hipStream_t stream) {
  const float* trg = (const float*)d_in[0];
  const float* src = (const float*)d_in[1];
  float* ctx = (float*)d_out;
  float* wts = (float*)d_out + (size_t)BB * TT * DD;

  const size_t NT = (size_t)BB * TT * DD;  // 16,777,216
  const size_t NW = (size_t)BB * TT * SS;  // 33,554,432
  const size_t need = (4 * NT + NW) * 2;   // 201,326,592 B = 192 MiB

  if (ws_size >= need) {
    _Float16* tH16 = (_Float16*)d_ws;
    _Float16* bhp  = tH16 + NT;
    _Float16* blp  = bhp + NT;
    _Float16* tp   = blp + NT;
    _Float16* w16  = tp + NT;

    conv_trg_f16<<<dim3(NT / (8 * 256)), 256, 0, stream>>>(trg, tH16);
    conv_src_frag<<<dim3(DD / 64, SS / 64, BB), 256, 0, stream>>>(src, bhp, blp, tp);
    attn_gemm1_pipe<<<dim3(SS / 256, TT / 256, BB), 512, 0, stream>>>(tH16, bhp, blp, wts);
    attn_softmax_w16<<<dim3(BB * TT), 64, 0, stream>>>(wts, w16);
    attn_gemm2_pipe<<<dim3(DD / 256, TT / 256, BB), 512, 0, stream>>>(w16, tp, ctx);
  } else {
    attn_gemm1_scores_bf16x3<<<dim3(SS / 128, TT / 128, BB), 256, 0, stream>>>(trg, src, wts);
    attn_softmax_rows<<<dim3(BB * TT), 256, 0, stream>>>(wts);
    attn_gemm2_ctx_f16<<<dim3(DD / 128, TT / 128, BB), 256, 0, stream>>>(wts, src, ctx);
  }
}

// Round 5
// 569.705 us; speedup vs baseline: 1.0344x; 1.0344x over previous
//
#include <hip/hip_runtime.h>

// Luong dot attention, B=8, T=S=2048, D=1024, fp32 in/out.
// Fast path (ws >= 128 MiB):
//   P1: trg -> fp16
//   P2: src -> fp16 hi + fp16 lo ([S][D]) + fp16 transposed hi ([D][S])
//   G1: scores = trg16 @ (srcHi+srcLo)^T, fp16 2-pass, 256x256 tile, BK=32,
//       triple-buffered LDS, per-phase lockstep, counted vmcnt (R2-measured best)
//   SM: softmax fp32 in place (no w16 intermediate)
//   G2: fused: read fp32 weights (L3-hot), cvt->f16 in-register, ds_write
//       bank-perfect dbuf A; B gl2lds dbuf; 16 MFMA + 1 barrier per K-tile.
// Fallback = round-1 kernels.

#define BB 8
#define TT 2048
#define SS 2048
#define DD 1024

typedef float  f32x4   __attribute__((ext_vector_type(4)));
typedef float  f32x16  __attribute__((ext_vector_type(16)));
typedef short  bf16x8  __attribute__((ext_vector_type(8)));
typedef _Float16 f16x8 __attribute__((ext_vector_type(8)));
typedef _Float16 f16x4 __attribute__((ext_vector_type(4)));

static __device__ __forceinline__ unsigned short bf16_rne(float x) {
  unsigned int u = __float_as_uint(x);
  u += 0x7FFFu + ((u >> 16) & 1u);
  return (unsigned short)(u >> 16);
}

static __device__ __forceinline__ void gl2lds16(const void* g, void* l) {
  __builtin_amdgcn_global_load_lds(
      (const __attribute__((address_space(1))) unsigned int*)g,
      (__attribute__((address_space(3))) unsigned int*)l, 16, 0, 0);
}

// Bank-perfect LDS layout for a 256x16-half region.
// Row r, half h: halves offset = (r>>2)*64 + (2*(r&3) + (h ^ ((r>>2)&1)))*8.
static __device__ __forceinline__ int ldsoff_h(int r, int h) {
  return ((r >> 2) << 6) + ((((r & 3) << 1) + (h ^ ((r >> 2) & 1))) << 3);
}

// ---------------------------------------------------------------------------
// P1: trg fp32 -> fp16 (single).
// ---------------------------------------------------------------------------
__global__ __launch_bounds__(256)
void conv_trg_f16(const float* __restrict__ x, _Float16* __restrict__ h16) {
  const size_t i = ((size_t)blockIdx.x * 256 + threadIdx.x) * 8;
  float4 v0 = *(const float4*)(x + i);
  float4 v1 = *(const float4*)(x + i + 4);
  f16x8 h;
  h[0] = (_Float16)v0.x; h[1] = (_Float16)v0.y;
  h[2] = (_Float16)v0.z; h[3] = (_Float16)v0.w;
  h[4] = (_Float16)v1.x; h[5] = (_Float16)v1.y;
  h[6] = (_Float16)v1.z; h[7] = (_Float16)v1.w;
  *(f16x8*)(h16 + i) = h;
}

// ---------------------------------------------------------------------------
// P2: src fp32 -> fp16 hi + fp16 lo ([S][D]) + fp16 transposed hi ([D][S]).
// ---------------------------------------------------------------------------
__global__ __launch_bounds__(256)
void conv_src_f16_hilo_t(const float* __restrict__ src,
                         _Float16* __restrict__ hi,
                         _Float16* __restrict__ lo,
                         _Float16* __restrict__ srcT) {
  const int b  = blockIdx.z;
  const int d0 = blockIdx.x * 64;
  const int s0 = blockIdx.y * 64;
  const float* S = src + (size_t)b * SS * DD;
  __shared__ _Float16 t16[64][65];
  const int t = threadIdx.x;

#pragma unroll
  for (int p = 0; p < 4; ++p) {
    const int r = p * 16 + (t >> 4);
    const int c = (t & 15) * 4;
    float4 v = *(const float4*)(S + (size_t)(s0 + r) * DD + d0 + c);
    float f[4] = {v.x, v.y, v.z, v.w};
    f16x4 h, l;
#pragma unroll
    for (int e = 0; e < 4; ++e) {
      _Float16 hv = (_Float16)f[e];
      h[e] = hv;
      l[e] = (_Float16)(f[e] - (float)hv);
      t16[r][c + e] = hv;
    }
    const size_t go = ((size_t)b * SS + s0 + r) * DD + d0 + c;
    *(f16x4*)(hi + go) = h;
    *(f16x4*)(lo + go) = l;
  }
  __syncthreads();
#pragma unroll
  for (int p = 0; p < 4; ++p) {
    const int d  = p * 16 + (t >> 4);
    const int sq = (t & 15) * 4;
    f16x4 o;
#pragma unroll
    for (int k = 0; k < 4; ++k) o[k] = t16[sq + k][d];
    *(f16x4*)(srcT + ((size_t)b * DD + d0 + d) * SS + s0 + sq) = o;
  }
}

// ---------------------------------------------------------------------------
// G1: scores = trg16 @ src16^T, fp16 2-pass (A single, B hi+lo).
// 256x256 tile, BK=32, 8 waves (2Mx4N, per-wave 128x64), 32x32x16 MFMA.
// Triple-buffered LDS, 2 lockstep phases per K-tile, counted vmcnt.
// (R2-measured best: 146 us)
// ---------------------------------------------------------------------------
__global__ __launch_bounds__(512, 2)
void attn_gemm1_pipe(const _Float16* __restrict__ a16,
                     const _Float16* __restrict__ bh16,
                     const _Float16* __restrict__ bl16,
                     float* __restrict__ scores) {
  const int b   = blockIdx.z;
  const int tm0 = blockIdx.y * 256;
  const int tn0 = blockIdx.x * 256;
  float* C = scores + (size_t)b * TT * SS;

  __shared__ __align__(16) _Float16 sm[3][24576];   // 144 KB

  const int t      = threadIdx.x;            // 0..511
  const int lane   = t & 63;
  const int wv     = t >> 6;                 // 0..7
  const int wm     = (wv >> 2) * 128;        // 0 / 128
  const int wn     = (wv & 3) * 64;          // 0..192
  const int lrow32 = lane & 31;
  const int khalf  = lane >> 5;

  // staging: 3072 16B-chunks per buffer; thread t covers chunks j*512+t.
  const _Float16* gp[6];
  {
    const _Float16* base0 = a16  + ((size_t)b * TT + tm0) * DD;
    const _Float16* base1 = bh16 + ((size_t)b * SS + tn0) * DD;
    const _Float16* base2 = bl16 + ((size_t)b * SS + tn0) * DD;
    const _Float16* bases[3] = {base0, base1, base2};
#pragma unroll
    for (int j = 0; j < 6; ++j) {
      const int kk   = j & 1;
      const int cc   = t;
      const int line = cc >> 3, slot = cc & 7;
      const int r    = (line << 2) + (slot >> 1);
      const int h    = (slot & 1) ^ (line & 1);
      gp[j] = bases[j >> 1] + (size_t)r * DD + kk * 16 + h * 8;
    }
  }
#define STG1(buf, j) do { gl2lds16(gp[j], (buf) + ((j) * 512 + t) * 8); gp[j] += 32; } while (0)

  int aoff[4], bhoff[2], bloff[2];
#pragma unroll
  for (int mi = 0; mi < 4; ++mi)
    aoff[mi] = ldsoff_h(wm + mi * 32 + lrow32, khalf);
#pragma unroll
  for (int ni = 0; ni < 2; ++ni) {
    const int rr = wn + ni * 32 + lrow32;
    bhoff[ni] = 8192  + ldsoff_h(rr, khalf);
    bloff[ni] = 16384 + ldsoff_h(rr, khalf);
  }

  f32x16 acc[4][2];
#pragma unroll
  for (int i = 0; i < 4; ++i)
#pragma unroll
    for (int j = 0; j < 2; ++j) acc[i][j] = (f32x16)0.0f;

  _Float16* bufc = sm[0];
  _Float16* bufo = sm[1];
  _Float16* bufn = sm[2];

#pragma unroll
  for (int j = 0; j < 6; ++j) STG1(bufc, j);
#pragma unroll
  for (int j = 0; j < 6; ++j) STG1(bufo, j);
  asm volatile("s_waitcnt vmcnt(6)" ::: "memory");
  __builtin_amdgcn_s_barrier();
  __builtin_amdgcn_sched_barrier(0);

  const int NT = DD / 32;  // 32 K-tiles
#pragma unroll 1
  for (int tt = 0; tt < NT; ++tt) {
    const bool more = (tt + 2 < NT);

    // ---- phase 0 (kk = 0) ----
    {
      f16x8 a[4], bh[2], bl[2];
#pragma unroll
      for (int mi = 0; mi < 4; ++mi) a[mi] = *(const f16x8*)(bufc + aoff[mi]);
#pragma unroll
      for (int ni = 0; ni < 2; ++ni) {
        bh[ni] = *(const f16x8*)(bufc + bhoff[ni]);
        bl[ni] = *(const f16x8*)(bufc + bloff[ni]);
      }
      if (more) { STG1(bufn, 0); STG1(bufn, 1); STG1(bufn, 2); }
      __builtin_amdgcn_s_barrier();
      asm volatile("s_waitcnt lgkmcnt(0)" ::: "memory");
      __builtin_amdgcn_sched_barrier(0);
      __builtin_amdgcn_s_setprio(1);
#pragma unroll
      for (int mi = 0; mi < 4; ++mi)
#pragma unroll
        for (int ni = 0; ni < 2; ++ni) {
          acc[mi][ni] = __builtin_amdgcn_mfma_f32_32x32x16_f16(a[mi], bh[ni], acc[mi][ni], 0, 0, 0);
          acc[mi][ni] = __builtin_amdgcn_mfma_f32_32x32x16_f16(a[mi], bl[ni], acc[mi][ni], 0, 0, 0);
        }
      __builtin_amdgcn_s_setprio(0);
      __builtin_amdgcn_s_barrier();
      __builtin_amdgcn_sched_barrier(0);
    }

    // ---- phase 1 (kk = 1) ----
    {
      f16x8 a[4], bh[2], bl[2];
#pragma unroll
      for (int mi = 0; mi < 4; ++mi) a[mi] = *(const f16x8*)(bufc + 4096 + aoff[mi]);
#pragma unroll
      for (int ni = 0; ni < 2; ++ni) {
        bh[ni] = *(const f16x8*)(bufc + 4096 + bhoff[ni]);
        bl[ni] = *(const f16x8*)(bufc + 4096 + bloff[ni]);
      }
      if (more) { STG1(bufn, 3); STG1(bufn, 4); STG1(bufn, 5); }
      if (more) asm volatile("s_waitcnt vmcnt(6)" ::: "memory");
      else      asm volatile("s_waitcnt vmcnt(0)" ::: "memory");
      __builtin_amdgcn_s_barrier();
      asm volatile("s_waitcnt lgkmcnt(0)" ::: "memory");
      __builtin_amdgcn_sched_barrier(0);
      __builtin_amdgcn_s_setprio(1);
#pragma unroll
      for (int mi = 0; mi < 4; ++mi)
#pragma unroll
        for (int ni = 0; ni < 2; ++ni) {
          acc[mi][ni] = __builtin_amdgcn_mfma_f32_32x32x16_f16(a[mi], bh[ni], acc[mi][ni], 0, 0, 0);
          acc[mi][ni] = __builtin_amdgcn_mfma_f32_32x32x16_f16(a[mi], bl[ni], acc[mi][ni], 0, 0, 0);
        }
      __builtin_amdgcn_s_setprio(0);
      __builtin_amdgcn_s_barrier();
      __builtin_amdgcn_sched_barrier(0);
    }

    _Float16* tmp = bufc; bufc = bufo; bufo = bufn; bufn = tmp;
  }
#undef STG1

  const int rsub = 4 * khalf;
#pragma unroll
  for (int mi = 0; mi < 4; ++mi)
#pragma unroll
    for (int ni = 0; ni < 2; ++ni) {
      const int rb  = tm0 + wm + mi * 32 + rsub;
      const int col = tn0 + wn + ni * 32 + lrow32;
#pragma unroll
      for (int p = 0; p < 16; ++p)
        C[(size_t)(rb + (p & 3) + 8 * (p >> 2)) * SS + col] = acc[mi][ni][p];
    }
}

// ---------------------------------------------------------------------------
// SM: softmax fp32 in place (single-wave blocks, no w16).
// ---------------------------------------------------------------------------
__global__ __launch_bounds__(64)
void attn_softmax_inplace(float* __restrict__ w) {
  const size_t row = blockIdx.x;
  float4* p4 = (float4*)(w + row * SS);
  const int lane = threadIdx.x;

  float4 v[8];
#pragma unroll
  for (int j = 0; j < 8; ++j) v[j] = p4[lane + 64 * j];

  float m = -1e30f;
#pragma unroll
  for (int j = 0; j < 8; ++j)
    m = fmaxf(m, fmaxf(fmaxf(v[j].x, v[j].y), fmaxf(v[j].z, v[j].w)));
#pragma unroll
  for (int off = 32; off >= 1; off >>= 1) m = fmaxf(m, __shfl_xor(m, off, 64));

  float s = 0.0f;
#pragma unroll
  for (int j = 0; j < 8; ++j) {
    v[j].x = __expf(v[j].x - m); v[j].y = __expf(v[j].y - m);
    v[j].z = __expf(v[j].z - m); v[j].w = __expf(v[j].w - m);
    s += v[j].x + v[j].y + v[j].z + v[j].w;
  }
#pragma unroll
  for (int off = 32; off >= 1; off >>= 1) s += __shfl_xor(s, off, 64);

  const float inv = __fdividef(1.0f, s);
#pragma unroll
  for (int j = 0; j < 8; ++j) {
    v[j].x *= inv; v[j].y *= inv; v[j].z *= inv; v[j].w *= inv;
    p4[lane + 64 * j] = v[j];
  }
}

// ---------------------------------------------------------------------------
// G2 fused: context = f16(w) @ srcT.
// 256x256 tile, BK=32, 64 K-tiles, 8 waves (2Mx4N, per-wave 128x64).
// A: fp32 weights loaded global->reg (2 tiles ahead), cvt->f16, ds_write into
//    bank-perfect dbuf. B: srcT staged via gl2lds (1 tile ahead), dbuf.
// One barrier per K-tile; counted vmcnt (w-loads never drained mid-loop).
// ---------------------------------------------------------------------------
__global__ __launch_bounds__(512, 2)
void attn_g2_fused(const float* __restrict__ w,
                   const _Float16* __restrict__ srcT,
                   float* __restrict__ out) {
  const int b   = blockIdx.z;
  const int tn0 = blockIdx.x * 256;   // d cols
  const int tm0 = blockIdx.y * 256;   // t rows
  const float* W = w + (size_t)b * TT * SS;
  float* C = out + (size_t)b * TT * DD;

  __shared__ __align__(16) _Float16 smA[2][8192];   // 16 KB each
  __shared__ __align__(16) _Float16 smB[2][8192];

  const int t      = threadIdx.x;
  const int lane   = t & 63;
  const int wv     = t >> 6;
  const int wm     = (wv >> 2) * 128;
  const int wn     = (wv & 3) * 64;
  const int lrow32 = lane & 31;
  const int khalf  = lane >> 5;

  // A-chunk mapping: p=0..3, c = p*512+t -> row rloc=c>>3, f4=c&7.
  const float* gw[4];
  int wadr[4];
#pragma unroll
  for (int p = 0; p < 4; ++p) {
    const int c    = p * 512 + t;
    const int rloc = c >> 3;
    const int f4   = c & 7;
    const int kk   = f4 >> 2;
    const int h    = (f4 >> 1) & 1;
    const int sub  = f4 & 1;
    wadr[p] = kk * 4096 + ldsoff_h(rloc, h) + sub * 4;
    gw[p] = W + (size_t)(tm0 + rloc) * SS + f4 * 4;
  }

  // B staging chunks (inverse of ldsoff_h), two kk regions.
  const int ar = (t >> 3) * 4 + ((t & 7) >> 1);
  const int ah = ((t & 7) & 1) ^ ((t >> 3) & 1);
  const _Float16* gpB0 = srcT + ((size_t)b * DD + tn0 + ar) * SS + ah * 8;
  const _Float16* gpB1 = gpB0 + 16;

  int aoff[4], boff[2];
#pragma unroll
  for (int mi = 0; mi < 4; ++mi)
    aoff[mi] = ldsoff_h(wm + mi * 32 + lrow32, khalf);
#pragma unroll
  for (int ni = 0; ni < 2; ++ni)
    boff[ni] = ldsoff_h(wn + ni * 32 + lrow32, khalf);

  f32x16 acc[4][2];
#pragma unroll
  for (int i = 0; i < 4; ++i)
#pragma unroll
    for (int j = 0; j < 2; ++j) acc[i][j] = (f32x16)0.0f;

  float4 wvA[4], wvB[4];

  _Float16* Ac = smA[0];
  _Float16* An = smA[1];
  _Float16* Bc = smB[0];
  _Float16* Bn = smB[1];

#define G2F_LOADW(S)                                   \
  do {                                                 \
    S[0] = *(const float4*)gw[0]; gw[0] += 32;         \
    S[1] = *(const float4*)gw[1]; gw[1] += 32;         \
    S[2] = *(const float4*)gw[2]; gw[2] += 32;         \
    S[3] = *(const float4*)gw[3]; gw[3] += 32;         \
  } while (0)

#define G2F_CVT(S, DST)                                                     \
  do {                                                                      \
    _Pragma("unroll") for (int p = 0; p < 4; ++p) {                         \
      f16x4 hh;                                                             \
      hh[0] = (_Float16)S[p].x; hh[1] = (_Float16)S[p].y;                   \
      hh[2] = (_Float16)S[p].z; hh[3] = (_Float16)S[p].w;                   \
      *(f16x4*)((DST) + wadr[p]) = hh;                                      \
    }                                                                       \
  } while (0)

#define G2F_STAGEB(DST)                                \
  do {                                                 \
    gl2lds16(gpB0, (DST) + t * 8);                     \
    gl2lds16(gpB1, (DST) + 4096 + t * 8);              \
    gpB0 += 32; gpB1 += 32;                            \
  } while (0)

#define G2F_MFMA_READS(A0, B0, A1, B1)                                      \
  f16x8 A0[4], B0[2], A1[4], B1[2];                                         \
  _Pragma("unroll") for (int mi = 0; mi < 4; ++mi)                          \
    A0[mi] = *(const f16x8*)(Ac + aoff[mi]);                                \
  _Pragma("unroll") for (int ni = 0; ni < 2; ++ni)                          \
    B0[ni] = *(const f16x8*)(Bc + boff[ni]);                                \
  _Pragma("unroll") for (int mi = 0; mi < 4; ++mi)                          \
    A1[mi] = *(const f16x8*)(Ac + 4096 + aoff[mi]);                         \
  _Pragma("unroll") for (int ni = 0; ni < 2; ++ni)                          \
    B1[ni] = *(const f16x8*)(Bc + 4096 + boff[ni]);

#define G2F_MFMA16(A0, B0, A1, B1)                                          \
  __builtin_amdgcn_s_setprio(1);                                            \
  _Pragma("unroll") for (int mi = 0; mi < 4; ++mi)                          \
    _Pragma("unroll") for (int ni = 0; ni < 2; ++ni)                        \
      acc[mi][ni] = __builtin_amdgcn_mfma_f32_32x32x16_f16(A0[mi], B0[ni], acc[mi][ni], 0, 0, 0); \
  _Pragma("unroll") for (int mi = 0; mi < 4; ++mi)                          \
    _Pragma("unroll") for (int ni = 0; ni < 2; ++ni)                        \
      acc[mi][ni] = __builtin_amdgcn_mfma_f32_32x32x16_f16(A1[mi], B1[ni], acc[mi][ni], 0, 0, 0); \
  __builtin_amdgcn_s_setprio(0);

// One K-tile iteration. WC = reg set holding w(tt+1) (consume), WL = set to
// load w(tt+2) into. DOB: stage B(tt+1). DOW: load w(tt+2). VME: end vmcnt.
#define G2F_ITER(WC, WL, DOB, DOW, VME)                                     \
  {                                                                         \
    if (DOB) G2F_STAGEB(Bn);                                                \
    G2F_MFMA_READS(a0, b0, a1, b1)                                          \
    asm volatile("s_waitcnt vmcnt(2)" ::: "memory");                        \
    G2F_CVT(WC, An);                                                        \
    if (DOW) G2F_LOADW(WL);                                                 \
    asm volatile("s_waitcnt lgkmcnt(0)" ::: "memory");                      \
    __builtin_amdgcn_sched_barrier(0);                                      \
    G2F_MFMA16(a0, b0, a1, b1)                                              \
    asm volatile("s_waitcnt vmcnt(" #VME ")" ::: "memory");                 \
    __builtin_amdgcn_s_barrier();                                           \
    __builtin_amdgcn_sched_barrier(0);                                      \
    _Float16* tA = Ac; Ac = An; An = tA;                                    \
    _Float16* tB = Bc; Bc = Bn; Bn = tB;                                    \
  }

  // Prologue: w(0), B(0); cvt A[0]; w(1); wait B(0).
  G2F_LOADW(wvA);                 // w(0) -> wvA
  G2F_STAGEB(Bc);                 // B(0) -> smB[0]
  asm volatile("s_waitcnt vmcnt(2)" ::: "memory");
  G2F_CVT(wvA, Ac);               // A[0]
  G2F_LOADW(wvA);                 // w(1) -> wvA (reused)
  asm volatile("s_waitcnt vmcnt(4)" ::: "memory");
  asm volatile("s_waitcnt lgkmcnt(0)" ::: "memory");
  __builtin_amdgcn_s_barrier();
  __builtin_amdgcn_sched_barrier(0);

#pragma unroll 1
  for (int it = 0; it < 31; ++it) {      // tt = 0..61
    G2F_ITER(wvA, wvB, 1, 1, 4);
    G2F_ITER(wvB, wvA, 1, 1, 4);
  }
  // tt = 62: consume wvA (w63), stage B(63), no new w loads.
  G2F_ITER(wvA, wvB, 1, 0, 0);
  // tt = 63: final compute, no staging, no barrier.
  {
    G2F_MFMA_READS(a0, b0, a1, b1)
    asm volatile("s_waitcnt lgkmcnt(0)" ::: "memory");
    __builtin_amdgcn_sched_barrier(0);
    G2F_MFMA16(a0, b0, a1, b1)
  }

#undef G2F_ITER
#undef G2F_MFMA16
#undef G2F_MFMA_READS
#undef G2F_STAGEB
#undef G2F_CVT
#undef G2F_LOADW

  const int rsub = 4 * khalf;
#pragma unroll
  for (int mi = 0; mi < 4; ++mi)
#pragma unroll
    for (int ni = 0; ni < 2; ++ni) {
      const int rb  = tm0 + wm + mi * 32 + rsub;
      const int col = tn0 + wn + ni * 32 + lrow32;
#pragma unroll
      for (int p = 0; p < 16; ++p)
        C[(size_t)(rb + (p & 3) + 8 * (p >> 2)) * DD + col] = acc[mi][ni][p];
    }
}

// ===========================================================================
// Fallback path (round-1 kernels, no workspace).
// ===========================================================================
__global__ __launch_bounds__(256, 1)
void attn_gemm1_scores_bf16x3(const float* __restrict__ trg,
                              const float* __restrict__ src,
                              float* __restrict__ scores) {
  const int b   = blockIdx.z;
  const int tm0 = blockIdx.y * 128;
  const int tn0 = blockIdx.x * 128;
  const float* A  = trg + (size_t)b * TT * DD;
  const float* Bm = src + (size_t)b * SS * DD;
  float* C = scores + (size_t)b * TT * SS;

  __shared__ __align__(16) unsigned short smAh[128 * 32];
  __shared__ __align__(16) unsigned short smAl[128 * 32];
  __shared__ __align__(16) unsigned short smBh[128 * 32];
  __shared__ __align__(16) unsigned short smBl[128 * 32];

  const int t     = threadIdx.x;
  const int lane  = t & 63;
  const int wv    = t >> 6;
  const int m_off = (wv & 1) * 64;
  const int n_off = (wv >> 1) * 64;
  const int q     = lane >> 4;
  const int lrow  = lane & 15;

  f32x4 acc[4][4];
#pragma unroll
  for (int i = 0; i < 4; ++i)
#pragma unroll
    for (int j = 0; j < 4; ++j) acc[i][j] = (f32x4)0.0f;

  for (int kt = 0; kt < DD; kt += 32) {
    __syncthreads();
#pragma unroll
    for (int h = 0; h < 2; ++h) {
      const int c  = t + h * 256;
      const int r  = c >> 2;
      const int j  = c & 3;
      const int gk = j ^ ((r >> 1) & 3);
      {
        const float* ga = A + (size_t)(tm0 + r) * DD + kt + gk * 8;
        float4 v0 = *(const float4*)ga;
        float4 v1 = *(const float4*)(ga + 4);
        float f[8] = {v0.x, v0.y, v0.z, v0.w, v1.x, v1.y, v1.z, v1.w};
        bf16x8 hi, lo;
#pragma unroll
        for (int e = 0; e < 8; ++e) {
          unsigned short hb = bf16_rne(f[e]);
          hi[e] = (short)hb;
          float hf = __uint_as_float(((unsigned int)hb) << 16);
          lo[e] = (short)bf16_rne(f[e] - hf);
        }
        *(bf16x8*)(smAh + c * 8) = hi;
        *(bf16x8*)(smAl + c * 8) = lo;
      }
      {
        const float* gb = Bm + (size_t)(tn0 + r) * DD + kt + gk * 8;
        float4 v0 = *(const float4*)gb;
        float4 v1 = *(const float4*)(gb + 4);
        float f[8] = {v0.x, v0.y, v0.z, v0.w, v1.x, v1.y, v1.z, v1.w};
        bf16x8 hi, lo;
#pragma unroll
        for (int e = 0; e < 8; ++e) {
          unsigned short hb = bf16_rne(f[e]);
          hi[e] = (short)hb;
          float hf = __uint_as_float(((unsigned int)hb) << 16);
          lo[e] = (short)bf16_rne(f[e] - hf);
        }
        *(bf16x8*)(smBh + c * 8) = hi;
        *(bf16x8*)(smBl + c * 8) = lo;
      }
    }
    __syncthreads();

    bf16x8 ah[4], al[4], bh[4], bl[4];
#pragma unroll
    for (int mi = 0; mi < 4; ++mi) {
      const int r   = m_off + mi * 16 + lrow;
      const int off = (r * 4 + (q ^ ((r >> 1) & 3))) * 8;
      ah[mi] = *(const bf16x8*)(smAh + off);
      al[mi] = *(const bf16x8*)(smAl + off);
    }
#pragma unroll
    for (int ni = 0; ni < 4; ++ni) {
      const int r   = n_off + ni * 16 + lrow;
      const int off = (r * 4 + (q ^ ((r >> 1) & 3))) * 8;
      bh[ni] = *(const bf16x8*)(smBh + off);
      bl[ni] = *(const bf16x8*)(smBl + off);
    }
#pragma unroll
    for (int mi = 0; mi < 4; ++mi)
#pragma unroll
      for (int ni = 0; ni < 4; ++ni) {
        acc[mi][ni] = __builtin_amdgcn_mfma_f32_16x16x32_bf16(al[mi], bh[ni], acc[mi][ni], 0, 0, 0);
        acc[mi][ni] = __builtin_amdgcn_mfma_f32_16x16x32_bf16(ah[mi], bl[ni], acc[mi][ni], 0, 0, 0);
        acc[mi][ni] = __builtin_amdgcn_mfma_f32_16x16x32_bf16(ah[mi], bh[ni], acc[mi][ni], 0, 0, 0);
      }
  }

#pragma unroll
  for (int mi = 0; mi < 4; ++mi)
#pragma unroll
    for (int ni = 0; ni < 4; ++ni) {
      const int row0 = tm0 + m_off + mi * 16 + q * 4;
      const int col  = tn0 + n_off + ni * 16 + lrow;
#pragma unroll
      for (int p = 0; p < 4; ++p)
        C[(size_t)(row0 + p) * SS + col] = acc[mi][ni][p];
    }
}

__global__ __launch_bounds__(256)
void attn_softmax_rows(float* __restrict__ w) {
  float* p = w + (size_t)blockIdx.x * SS;
  const int t = threadIdx.x;
  float4* p4 = (float4*)p;
  float4 v0 = p4[t];
  float4 v1 = p4[t + 256];

  float m = fmaxf(fmaxf(fmaxf(v0.x, v0.y), fmaxf(v0.z, v0.w)),
                  fmaxf(fmaxf(v1.x, v1.y), fmaxf(v1.z, v1.w)));
#pragma unroll
  for (int off = 32; off >= 1; off >>= 1) m = fmaxf(m, __shfl_xor(m, off, 64));
  __shared__ float redm[4];
  __shared__ float reds[4];
  const int wv = t >> 6, lane = t & 63;
  if (lane == 0) redm[wv] = m;
  __syncthreads();
  m = fmaxf(fmaxf(redm[0], redm[1]), fmaxf(redm[2], redm[3]));

  v0.x = __expf(v0.x - m); v0.y = __expf(v0.y - m);
  v0.z = __expf(v0.z - m); v0.w = __expf(v0.w - m);
  v1.x = __expf(v1.x - m); v1.y = __expf(v1.y - m);
  v1.z = __expf(v1.z - m); v1.w = __expf(v1.w - m);

  float s = v0.x + v0.y + v0.z + v0.w + v1.x + v1.y + v1.z + v1.w;
#pragma unroll
  for (int off = 32; off >= 1; off >>= 1) s += __shfl_xor(s, off, 64);
  if (lane == 0) reds[wv] = s;
  __syncthreads();
  s = reds[0] + reds[1] + reds[2] + reds[3];

  const float inv = __fdividef(1.0f, s);
  v0.x *= inv; v0.y *= inv; v0.z *= inv; v0.w *= inv;
  v1.x *= inv; v1.y *= inv; v1.z *= inv; v1.w *= inv;
  p4[t] = v0;
  p4[t + 256] = v1;
}

__global__ __launch_bounds__(256, 1)
void attn_gemm2_ctx_f16(const float* __restrict__ w,
                        const float* __restrict__ src,
                        float* __restrict__ out) {
  const int b   = blockIdx.z;
  const int tm0 = blockIdx.y * 128;
  const int tn0 = blockIdx.x * 128;
  const float* A  = w + (size_t)b * TT * SS;
  const float* Bs = src + (size_t)b * SS * DD;
  float* C = out + (size_t)b * TT * DD;

  __shared__ __align__(16) _Float16 smA[128 * 32];
  __shared__ __align__(16) _Float16 smB[128 * 32];

  const int t     = threadIdx.x;
  const int lane  = t & 63;
  const int wv    = t >> 6;
  const int m_off = (wv & 1) * 64;
  const int n_off = (wv >> 1) * 64;
  const int q     = lane >> 4;
  const int lrow  = lane & 15;

  const int bn    = t & 127;
  const int bh2   = t >> 7;
  const int bs2   = (bn >> 1) & 3;
  const int slot0 = (2 * bh2) ^ bs2;
  const int slot1 = (2 * bh2 + 1) ^ bs2;

  f32x4 acc[4][4];
#pragma unroll
  for (int i = 0; i < 4; ++i)
#pragma unroll
    for (int j = 0; j < 4; ++j) acc[i][j] = (f32x4)0.0f;

  for (int kt = 0; kt < SS; kt += 32) {
    __syncthreads();
#pragma unroll
    for (int h = 0; h < 2; ++h) {
      const int c  = t + h * 256;
      const int r  = c >> 2;
      const int j  = c & 3;
      const int gk = j ^ ((r >> 1) & 3);
      const float* ga = A + (size_t)(tm0 + r) * SS + kt + gk * 8;
      float4 v0 = *(const float4*)ga;
      float4 v1 = *(const float4*)(ga + 4);
      f16x8 hv;
      hv[0] = (_Float16)v0.x; hv[1] = (_Float16)v0.y;
      hv[2] = (_Float16)v0.z; hv[3] = (_Float16)v0.w;
      hv[4] = (_Float16)v1.x; hv[5] = (_Float16)v1.y;
      hv[6] = (_Float16)v1.z; hv[7] = (_Float16)v1.w;
      *(f16x8*)(smA + c * 8) = hv;
    }
    {
      const float* gb = Bs + (size_t)(kt + bh2 * 16) * DD + (tn0 + bn);
      f16x8 c0, c1;
#pragma unroll
      for (int kk = 0; kk < 8; ++kk) c0[kk] = (_Float16)gb[(size_t)kk * DD];
#pragma unroll
      for (int kk = 0; kk < 8; ++kk) c1[kk] = (_Float16)gb[(size_t)(kk + 8) * DD];
      *(f16x8*)(smB + bn * 32 + slot0 * 8) = c0;
      *(f16x8*)(smB + bn * 32 + slot1 * 8) = c1;
    }
    __syncthreads();

    f16x8 af[4], bfr[4];
#pragma unroll
    for (int mi = 0; mi < 4; ++mi) {
      const int r   = m_off + mi * 16 + lrow;
      const int off = (r * 4 + (q ^ ((r >> 1) & 3))) * 8;
      af[mi] = *(const f16x8*)(smA + off);
    }
#pragma unroll
    for (int ni = 0; ni < 4; ++ni) {
      const int n   = n_off + ni * 16 + lrow;
      const int off = n * 32 + (q ^ ((n >> 1) & 3)) * 8;
      bfr[ni] = *(const f16x8*)(smB + off);
    }
#pragma unroll
    for (int mi = 0; mi < 4; ++mi)
#pragma unroll
      for (int ni = 0; ni < 4; ++ni)
        acc[mi][ni] = __builtin_amdgcn_mfma_f32_16x16x32_f16(af[mi], bfr[ni], acc[mi][ni], 0, 0, 0);
  }

#pragma unroll
  for (int mi = 0; mi < 4; ++mi)
#pragma unroll
    for (int ni = 0; ni < 4; ++ni) {
      const int row0 = tm0 + m_off + mi * 16 + q * 4;
      const int col  = tn0 + n_off + ni * 16 + lrow;
#pragma unroll
      for (int p = 0; p < 4; ++p)
        C[(size_t)(row0 + p) * DD + col] = acc[mi][ni][p];
    }
}

extern "C" void kernel_launch(void* const* d_in, const int* in_sizes, int n_in,
                              void* d_out, int out_size, void* d_ws, size_t ws_size,
                              hipStream_t stream) {
  const float* trg = (const float*)d_in[0];
  const float* src = (const float*)d_in[1];
  float* ctx = (float*)d_out;
  float* wts = (float*)d_out + (size_t)BB * TT * DD;

  const size_t NT = (size_t)BB * TT * DD;  // 16,777,216
  const size_t need = 4 * NT * 2;          // 134,217,728 B = 128 MiB

  if (ws_size >= need) {
    _Float16* tH16 = (_Float16*)d_ws;
    _Float16* sH16 = tH16 + NT;
    _Float16* sL16 = sH16 + NT;
    _Float16* srcT = sL16 + NT;

    conv_trg_f16<<<dim3(NT / (8 * 256)), 256, 0, stream>>>(trg, tH16);
    conv_src_f16_hilo_t<<<dim3(DD / 64, SS / 64, BB), 256, 0, stream>>>(src, sH16, sL16, srcT);
    attn_gemm1_pipe<<<dim3(SS / 256, TT / 256, BB), 512, 0, stream>>>(tH16, sH16, sL16, wts);
    attn_softmax_inplace<<<dim3(BB * TT), 64, 0, stream>>>(wts);
    attn_g2_fused<<<dim3(DD / 256, TT / 256, BB), 512, 0, stream>>>(wts, srcT, ctx);
  } else {
    attn_gemm1_scores_bf16x3<<<dim3(SS / 128, TT / 128, BB), 256, 0, stream>>>(trg, src, wts);
    attn_softmax_rows<<<dim3(BB * TT), 256, 0, stream>>>(wts);
    attn_gemm2_ctx_f16<<<dim3(DD / 128, TT / 128, BB), 256, 0, stream>>>(wts, src, ctx);
  }
}